// Round 4
// baseline (154.772 us; speedup 1.0000x reference)
//
#include <hip/hip_runtime.h>
#include <hip/hip_bf16.h>

#define B_ 16
#define C_ 128
#define D_ 256

typedef unsigned int uint32;

// unpack 2 packed bf16 (little-endian: low ushort = even element) to 2 floats
__device__ __forceinline__ float2 bf2x(uint32 x) {
  return make_float2(__uint_as_float(x << 16), __uint_as_float(x & 0xffff0000u));
}

// ---------------------------------------------------------------------------
// K1: P[row,k] = sum_d h[row,d]*W1[d,k]; Q[row,k] = sum_d h[row,d]*W1[D+d,k]+b1[k]
// Outputs stored bf16 (only k2 consumes them).
// Block: 8 rows x 128 vcols (vcol space 512). 256 thr = 128c x 2 rowgroups x 4 rows.
// Grid (4,256) = 1024 blocks -> 4 blocks/CU.
// ---------------------------------------------------------------------------
__global__ __launch_bounds__(256) void k1_pq(const float* __restrict__ h,
                                             const float* __restrict__ W1,
                                             const float* __restrict__ b1,
                                             __hip_bfloat16* __restrict__ P,
                                             __hip_bfloat16* __restrict__ Q) {
  const int tid = threadIdx.x;
  const int vcol = blockIdx.x * 128 + (tid & 127);   // 0..511
  const int rb = (tid >> 7) * 4;                     // 0 or 4
  const int row0 = blockIdx.y * 8;
  __shared__ float hs[8][D_];
#pragma unroll
  for (int r = 0; r < 8; ++r) hs[r][tid] = h[(row0 + r) * D_ + tid];
  __syncthreads();

  const int c = vcol & 255;
  const float* Wcol = W1 + c + ((vcol & 256) << 8);  // Q-half offset = 256*256

  float acc[4] = {0.f, 0.f, 0.f, 0.f};
#pragma unroll 4
  for (int d = 0; d < D_; d += 4) {
    const float w0 = Wcol[(d + 0) * D_];
    const float w1 = Wcol[(d + 1) * D_];
    const float w2 = Wcol[(d + 2) * D_];
    const float w3 = Wcol[(d + 3) * D_];
#pragma unroll
    for (int i = 0; i < 4; ++i) {
      const float4 hv = *(const float4*)&hs[rb + i][d];
      acc[i] = fmaf(hv.x, w0, fmaf(hv.y, w1, fmaf(hv.z, w2, fmaf(hv.w, w3, acc[i]))));
    }
  }

  if (vcol < 256) {
#pragma unroll
    for (int i = 0; i < 4; ++i)
      P[(row0 + rb + i) * D_ + c] = __float2bfloat16(acc[i]);
  } else {
    const float bb = b1[c];
#pragma unroll
    for (int i = 0; i < 4; ++i)
      Q[(row0 + rb + i) * D_ + c] = __float2bfloat16(acc[i] + bb);
  }
}

// ---------------------------------------------------------------------------
// K2: SA_T[b,v,u] = sigmoid( sum_k relu(P[b,u,k]+Q[b,v,k])*W2[k] + b2 ) * Aa[u,v]
// 16x16 (u,v) tile / block, 1 output/thread (u = tid&15 fast -> coalesced store).
// P/Q tiles in LDS as packed bf16 pairs, row pad 1 uint -> conflict-free
// row-broadcast reads. W2 wave-uniform (s_load). Grid (8,8,16) = 1024 blocks.
// ---------------------------------------------------------------------------
__global__ __launch_bounds__(256) void k2_s(const __hip_bfloat16* __restrict__ P,
                                            const __hip_bfloat16* __restrict__ Q,
                                            const float* __restrict__ W2,
                                            const float* __restrict__ b2,
                                            const float* __restrict__ Aa,
                                            float* __restrict__ SA) {
  const int b = blockIdx.z;
  const int u0 = blockIdx.x * 16;
  const int v0 = blockIdx.y * 16;
  const int tid = threadIdx.x;
  __shared__ uint32 Pl[16][129];
  __shared__ uint32 Ql[16][129];
  const uint32* Pg = (const uint32*)(P + (b * C_ + u0) * D_);
  const uint32* Qg = (const uint32*)(Q + (b * C_ + v0) * D_);
#pragma unroll
  for (int i = 0; i < 8; ++i) {
    const int idx = i * 256 + tid;
    const int r = idx >> 7, kk = idx & 127;
    Pl[r][kk] = Pg[r * 128 + kk];
    Ql[r][kk] = Qg[r * 128 + kk];
  }
  __syncthreads();

  const int ul = tid & 15;   // u local (fast -> coalesced store)
  const int vl = tid >> 4;   // v local
  const float2* __restrict__ w2v = (const float2*)W2;

  float a = 0.f;
#pragma unroll 8
  for (int kk = 0; kk < 128; ++kk) {
    const float2 p = bf2x(Pl[ul][kk]);
    const float2 q = bf2x(Ql[vl][kk]);
    const float2 w = w2v[kk];
    a = fmaf(fmaxf(p.x + q.x, 0.f), w.x, a);
    a = fmaf(fmaxf(p.y + q.y, 0.f), w.y, a);
  }
  const float s = 1.f / (1.f + __expf(-(a + b2[0])));
  const int u = u0 + ul, v = v0 + vl;
  SA[b * C_ * C_ + v * C_ + u] = s * Aa[u * C_ + v];
}

// ---------------------------------------------------------------------------
// K3: AT[b,v,d] = sum_u SA_T[b,v,u]*h[b,u,d]; MT = (sum_u Am[u,v]*h[b,u,d])*h[b,v,d]
// Block: 2 v-rows x 256 d. Grid (64,16) = 1024 blocks.
// ---------------------------------------------------------------------------
__global__ __launch_bounds__(256) void k3_agg(const float* __restrict__ SA,
                                              const float* __restrict__ Am,
                                              const float* __restrict__ h,
                                              float* __restrict__ AT,
                                              float* __restrict__ MT) {
  const int b = blockIdx.y;
  const int v0 = blockIdx.x * 2;
  const int tid = threadIdx.x;
  __shared__ float SAl[2][128];
  __shared__ float AmT[2][128];
  {
    const int r = tid >> 7, uu = tid & 127;
    SAl[r][uu] = SA[b * C_ * C_ + (v0 + r) * C_ + uu];
    AmT[r][uu] = Am[uu * C_ + (v0 + r)];
  }
  __syncthreads();
  const float* hb = h + b * C_ * D_;
  float a0 = 0.f, a1 = 0.f, m0 = 0.f, m1 = 0.f;
#pragma unroll 8
  for (int u = 0; u < C_; ++u) {
    const float hv = hb[u * D_ + tid];
    a0 = fmaf(SAl[0][u], hv, a0);
    a1 = fmaf(SAl[1][u], hv, a1);
    m0 = fmaf(AmT[0][u], hv, m0);
    m1 = fmaf(AmT[1][u], hv, m1);
  }
  const float h0 = hb[(v0 + 0) * D_ + tid];
  const float h1 = hb[(v0 + 1) * D_ + tid];
  AT[(b * C_ + v0 + 0) * D_ + tid] = a0;
  AT[(b * C_ + v0 + 1) * D_ + tid] = a1;
  MT[(b * C_ + v0 + 0) * D_ + tid] = m0 * h0;
  MT[(b * C_ + v0 + 1) * D_ + tid] = m1 * h1;
}

// ---------------------------------------------------------------------------
// K4: z = beta1*h + beta2*(AT@Wa + ba) + beta3*(MT@Wm + bm)
// Block: 8 rows x 128 cols, 256 thr = 128c x 2 rowgroups x 4 rows.
// Grid (2,256) = 512 blocks (2/CU; halves L2 W-traffic vs 4-row tiles).
// ---------------------------------------------------------------------------
__global__ __launch_bounds__(256) void k4_out(const float* __restrict__ h,
                                              const float* __restrict__ AT,
                                              const float* __restrict__ MT,
                                              const float* __restrict__ Wa,
                                              const float* __restrict__ ba,
                                              const float* __restrict__ Wm,
                                              const float* __restrict__ bm,
                                              const float* __restrict__ be1,
                                              const float* __restrict__ be2,
                                              const float* __restrict__ be3,
                                              float* __restrict__ z) {
  const int tid = threadIdx.x;
  const int col = blockIdx.x * 128 + (tid & 127);
  const int rb = (tid >> 7) * 4;
  const int row0 = blockIdx.y * 8;
  __shared__ float As[8][D_];
  __shared__ float Ms[8][D_];
#pragma unroll
  for (int r = 0; r < 8; ++r) {
    As[r][tid] = AT[(row0 + r) * D_ + tid];
    Ms[r][tid] = MT[(row0 + r) * D_ + tid];
  }
  __syncthreads();

  const float* WaC = Wa + col;
  const float* WmC = Wm + col;
  float accA[4] = {0.f, 0.f, 0.f, 0.f};
  float accM[4] = {0.f, 0.f, 0.f, 0.f};
#pragma unroll 4
  for (int d = 0; d < D_; d += 4) {
    const float wa0 = WaC[(d + 0) * D_];
    const float wa1 = WaC[(d + 1) * D_];
    const float wa2 = WaC[(d + 2) * D_];
    const float wa3 = WaC[(d + 3) * D_];
    const float wm0 = WmC[(d + 0) * D_];
    const float wm1 = WmC[(d + 1) * D_];
    const float wm2 = WmC[(d + 2) * D_];
    const float wm3 = WmC[(d + 3) * D_];
#pragma unroll
    for (int i = 0; i < 4; ++i) {
      const float4 av = *(const float4*)&As[rb + i][d];
      const float4 mv = *(const float4*)&Ms[rb + i][d];
      accA[i] = fmaf(av.x, wa0, fmaf(av.y, wa1, fmaf(av.z, wa2, fmaf(av.w, wa3, accA[i]))));
      accM[i] = fmaf(mv.x, wm0, fmaf(mv.y, wm1, fmaf(mv.z, wm2, fmaf(mv.w, wm3, accM[i]))));
    }
  }

  const float b1v = be1[0], b2v = be2[0], b3v = be3[0];
  const float bav = ba[col], bmv = bm[col];
#pragma unroll
  for (int i = 0; i < 4; ++i) {
    const int row = row0 + rb + i;
    const float hv = h[row * D_ + col];
    z[row * D_ + col] = b1v * hv + b2v * (accA[i] + bav) + b3v * (accM[i] + bmv);
  }
}

extern "C" void kernel_launch(void* const* d_in, const int* in_sizes, int n_in,
                              void* d_out, int out_size, void* d_ws, size_t ws_size,
                              hipStream_t stream) {
  const float* h   = (const float*)d_in[0];
  const float* Aa  = (const float*)d_in[1];
  const float* Am  = (const float*)d_in[2];
  const float* W1  = (const float*)d_in[3];
  const float* b1  = (const float*)d_in[4];
  const float* W2  = (const float*)d_in[5];
  const float* b2  = (const float*)d_in[6];
  const float* Wa  = (const float*)d_in[7];
  const float* ba  = (const float*)d_in[8];
  const float* Wm  = (const float*)d_in[9];
  const float* bm  = (const float*)d_in[10];
  const float* be1 = (const float*)d_in[11];
  const float* be2 = (const float*)d_in[12];
  const float* be3 = (const float*)d_in[13];
  float* z = (float*)d_out;

  char* wsb = (char*)d_ws;
  __hip_bfloat16* P = (__hip_bfloat16*)wsb;                    // 2048*256*2B = 1MB
  __hip_bfloat16* Q = P + (B_ * C_ * D_);                      // 1MB
  float* SA = (float*)(wsb + 2 * (size_t)(B_ * C_ * D_) * 2);  // [b][v][u], 1MB
  float* AT = SA + (B_ * C_ * C_);                             // 2MB
  float* MT = AT + (B_ * C_ * D_);                             // 2MB

  k1_pq <<<dim3(4, 256),   256, 0, stream>>>(h, W1, b1, P, Q);
  k2_s  <<<dim3(8, 8, 16), 256, 0, stream>>>(P, Q, W2, b2, Aa, SA);
  k3_agg<<<dim3(64, 16),   256, 0, stream>>>(SA, Am, h, AT, MT);
  k4_out<<<dim3(2, 256),   256, 0, stream>>>(h, AT, MT, Wa, ba, Wm, bm, be1, be2, be3, z);
}

// Round 6
// 147.327 us; speedup vs baseline: 1.0505x; 1.0505x over previous
//
#include <hip/hip_runtime.h>
#include <hip/hip_bf16.h>

#define B_ 16
#define C_ 128
#define D_ 256

typedef unsigned int uint32;

// unpack 2 packed bf16 (low ushort = even element) to 2 floats
__device__ __forceinline__ float2 bf2x(uint32 x) {
  return make_float2(__uint_as_float(x << 16), __uint_as_float(x & 0xffff0000u));
}
__device__ __forceinline__ uint32 packbf(float a, float b) {
  union U { __hip_bfloat16 h; unsigned short s; } ua, ub;
  ua.h = __float2bfloat16(a);
  ub.h = __float2bfloat16(b);
  return (uint32)ua.s | ((uint32)ub.s << 16);
}

// ---------------------------------------------------------------------------
// K1: P[row,k]=sum_d h[row,d]*W1[d,k]; Q[row,k]=sum_d h[row,d]*W1[D+d,k]+b1[k]
// vcol space 512 (0..255 -> P, 256..511 -> Q). Block: 8 rows x 64 vcols,
// 256 thr = 64 cols x 4 rowgroups x 2 rows. LDS h = 8KB. Grid (8,256)=2048
// blocks -> 8 blocks/CU -> 32 waves/CU. W1 slabs L2-resident.
// ---------------------------------------------------------------------------
__global__ __launch_bounds__(256) void k1_pq(const float* __restrict__ h,
                                             const float* __restrict__ W1,
                                             const float* __restrict__ b1,
                                             __hip_bfloat16* __restrict__ P,
                                             __hip_bfloat16* __restrict__ Q) {
  const int tid = threadIdx.x;
  const int vcol = blockIdx.x * 64 + (tid & 63);   // 0..511, uniform half/block
  const int rg = tid >> 6;                         // 0..3 -> rows rg*2, rg*2+1
  const int row0 = blockIdx.y * 8;
  __shared__ float hs[8][D_];
  {  // stage 8 rows (2048 floats) as float4: 512 lanes-worth, 2 per thread
    const float4* hg = (const float4*)(h + row0 * D_);
    float4* hsv = (float4*)&hs[0][0];
    hsv[tid] = hg[tid];
    hsv[tid + 256] = hg[tid + 256];
  }
  __syncthreads();

  const int c = vcol & 255;
  const float* Wcol = W1 + c + ((vcol & 256) << 8);  // Q-half offset 256*256

  float acc[2] = {0.f, 0.f};
#pragma unroll 8
  for (int d = 0; d < D_; d += 4) {
    const float w0 = Wcol[(d + 0) * D_];
    const float w1 = Wcol[(d + 1) * D_];
    const float w2 = Wcol[(d + 2) * D_];
    const float w3 = Wcol[(d + 3) * D_];
#pragma unroll
    for (int i = 0; i < 2; ++i) {
      const float4 hv = *(const float4*)&hs[rg * 2 + i][d];  // wave-broadcast
      acc[i] = fmaf(hv.x, w0, fmaf(hv.y, w1, fmaf(hv.z, w2, fmaf(hv.w, w3, acc[i]))));
    }
  }

  if (vcol < 256) {
#pragma unroll
    for (int i = 0; i < 2; ++i)
      P[(row0 + rg * 2 + i) * D_ + c] = __float2bfloat16(acc[i]);
  } else {
    const float bb = b1[c];
#pragma unroll
    for (int i = 0; i < 2; ++i)
      Q[(row0 + rg * 2 + i) * D_ + c] = __float2bfloat16(acc[i] + bb);
  }
}

// ---------------------------------------------------------------------------
// K2: SA_T[b,v,u] = sigmoid( sum_k relu(P[b,u,k]+Q[b,v,k])*W2[k]+b2 ) * Aa[u,v]
// 16x16 uv-tile, 1 output/thread. P/Q tiles packed bf16 in LDS (pad 129 ->
// conflict-free broadcast rows). 2 accumulators. LDS 16.5KB.
// Grid (8,8,16) = 1024 blocks -> 4 blocks/CU -> 16 waves/CU.
// ---------------------------------------------------------------------------
__global__ __launch_bounds__(256) void k2_s(const __hip_bfloat16* __restrict__ P,
                                            const __hip_bfloat16* __restrict__ Q,
                                            const float* __restrict__ W2,
                                            const float* __restrict__ b2,
                                            const float* __restrict__ Aa,
                                            float* __restrict__ SA) {
  const int b = blockIdx.z;
  const int u0 = blockIdx.x * 16;
  const int v0 = blockIdx.y * 16;
  const int tid = threadIdx.x;
  __shared__ uint32 Pl[16][129];
  __shared__ uint32 Ql[16][129];
  const uint32* Pg = (const uint32*)(P + (b * C_ + u0) * D_);
  const uint32* Qg = (const uint32*)(Q + (b * C_ + v0) * D_);
#pragma unroll
  for (int i = 0; i < 8; ++i) {
    const int idx = i * 256 + tid;
    const int r = idx >> 7, kk = idx & 127;
    Pl[r][kk] = Pg[r * 128 + kk];
    Ql[r][kk] = Qg[r * 128 + kk];
  }
  __syncthreads();

  const int ul = tid & 15;   // u local (fast -> coalesced store)
  const int vl = tid >> 4;   // v local
  const float2* __restrict__ w2v = (const float2*)W2;

  float a0 = 0.f, a1 = 0.f;
#pragma unroll 8
  for (int kk = 0; kk < 128; kk += 2) {
    const uint32 pu0 = Pl[ul][kk],     pu1 = Pl[ul][kk + 1];
    const uint32 qu0 = Ql[vl][kk],     qu1 = Ql[vl][kk + 1];
    const float2 p0 = bf2x(pu0), p1 = bf2x(pu1);
    const float2 q0 = bf2x(qu0), q1 = bf2x(qu1);
    const float2 w0 = w2v[kk],   w1 = w2v[kk + 1];
    a0 = fmaf(fmaxf(p0.x + q0.x, 0.f), w0.x, a0);
    a0 = fmaf(fmaxf(p0.y + q0.y, 0.f), w0.y, a0);
    a1 = fmaf(fmaxf(p1.x + q1.x, 0.f), w1.x, a1);
    a1 = fmaf(fmaxf(p1.y + q1.y, 0.f), w1.y, a1);
  }
  const float s = 1.f / (1.f + __expf(-(a0 + a1 + b2[0])));
  const int u = u0 + ul, v = v0 + vl;
  SA[b * C_ * C_ + v * C_ + u] = s * Aa[u * C_ + v];
}

// ---------------------------------------------------------------------------
// K3: AT[b,v,d]=sum_u SA_T[b,v,u]*h[b,u,d]; MT=(sum_u Am[u,v]*h[b,u,d])*h[b,v,d]
// Block: 2 v-rows x 256 d. Grid (64,16) = 1024 blocks -> 16 waves/CU.
// ---------------------------------------------------------------------------
__global__ __launch_bounds__(256) void k3_agg(const float* __restrict__ SA,
                                              const float* __restrict__ Am,
                                              const float* __restrict__ h,
                                              float* __restrict__ AT,
                                              float* __restrict__ MT) {
  const int b = blockIdx.y;
  const int v0 = blockIdx.x * 2;
  const int tid = threadIdx.x;
  __shared__ float SAl[2][128];
  __shared__ float AmT[2][128];
  {
    const int r = tid >> 7, uu = tid & 127;
    SAl[r][uu] = SA[b * C_ * C_ + (v0 + r) * C_ + uu];
    AmT[r][uu] = Am[uu * C_ + (v0 + r)];
  }
  __syncthreads();
  const float* hb = h + b * C_ * D_;
  float a0 = 0.f, a1 = 0.f, m0 = 0.f, m1 = 0.f;
#pragma unroll 16
  for (int u = 0; u < C_; ++u) {
    const float hv = hb[u * D_ + tid];
    a0 = fmaf(SAl[0][u], hv, a0);
    a1 = fmaf(SAl[1][u], hv, a1);
    m0 = fmaf(AmT[0][u], hv, m0);
    m1 = fmaf(AmT[1][u], hv, m1);
  }
  const float h0 = hb[(v0 + 0) * D_ + tid];
  const float h1 = hb[(v0 + 1) * D_ + tid];
  AT[(b * C_ + v0 + 0) * D_ + tid] = a0;
  AT[(b * C_ + v0 + 1) * D_ + tid] = a1;
  MT[(b * C_ + v0 + 0) * D_ + tid] = m0 * h0;
  MT[(b * C_ + v0 + 1) * D_ + tid] = m1 * h1;
}

// ---------------------------------------------------------------------------
// K4: z = beta1*h + beta2*(AT@Wa + ba) + beta3*(MT@Wm + bm)
// Block: 8 rows x 64 cols (col space 256!). 256 thr = 64c x 4 rowgroups x
// 2 rows. AT/MT staged packed bf16 (8KB LDS). Grid (4,256) = 1024 blocks
// -> 4 blocks/CU -> 16 waves/CU. W slabs L2-resident.
// ---------------------------------------------------------------------------
__global__ __launch_bounds__(256) void k4_out(const float* __restrict__ h,
                                              const float* __restrict__ AT,
                                              const float* __restrict__ MT,
                                              const float* __restrict__ Wa,
                                              const float* __restrict__ ba,
                                              const float* __restrict__ Wm,
                                              const float* __restrict__ bm,
                                              const float* __restrict__ be1,
                                              const float* __restrict__ be2,
                                              const float* __restrict__ be3,
                                              float* __restrict__ z) {
  const int tid = threadIdx.x;
  const int col = blockIdx.x * 64 + (tid & 63);    // 0..255
  const int rg = tid >> 6;                         // 0..3
  const int row0 = blockIdx.y * 8;
  __shared__ uint32 Asp[8][128];   // packed bf16 pairs along d
  __shared__ uint32 Msp[8][128];
#pragma unroll
  for (int i = 0; i < 4; ++i) {
    const int idx = i * 256 + tid;                 // 0..1023
    const int r = idx >> 7, pp = idx & 127;
    const float2 av = *(const float2*)&AT[(row0 + r) * D_ + 2 * pp];
    const float2 mv = *(const float2*)&MT[(row0 + r) * D_ + 2 * pp];
    Asp[r][pp] = packbf(av.x, av.y);
    Msp[r][pp] = packbf(mv.x, mv.y);
  }
  __syncthreads();

  const float* WaC = Wa + col;
  const float* WmC = Wm + col;
  float accA[2] = {0.f, 0.f};
  float accM[2] = {0.f, 0.f};
#pragma unroll 8
  for (int d = 0; d < D_; d += 4) {
    const float wa0 = WaC[(d + 0) * D_];
    const float wa1 = WaC[(d + 1) * D_];
    const float wa2 = WaC[(d + 2) * D_];
    const float wa3 = WaC[(d + 3) * D_];
    const float wm0 = WmC[(d + 0) * D_];
    const float wm1 = WmC[(d + 1) * D_];
    const float wm2 = WmC[(d + 2) * D_];
    const float wm3 = WmC[(d + 3) * D_];
#pragma unroll
    for (int i = 0; i < 2; ++i) {
      const int r = rg * 2 + i;
      const float2 a01 = bf2x(Asp[r][d >> 1]);       // broadcast reads
      const float2 a23 = bf2x(Asp[r][(d >> 1) + 1]);
      const float2 m01 = bf2x(Msp[r][d >> 1]);
      const float2 m23 = bf2x(Msp[r][(d >> 1) + 1]);
      accA[i] = fmaf(a01.x, wa0, fmaf(a01.y, wa1, fmaf(a23.x, wa2, fmaf(a23.y, wa3, accA[i]))));
      accM[i] = fmaf(m01.x, wm0, fmaf(m01.y, wm1, fmaf(m23.x, wm2, fmaf(m23.y, wm3, accM[i]))));
    }
  }

  const float b1v = be1[0], b2v = be2[0], b3v = be3[0];
  const float bav = ba[col], bmv = bm[col];
#pragma unroll
  for (int i = 0; i < 2; ++i) {
    const int row = row0 + rg * 2 + i;
    const float hv = h[row * D_ + col];
    z[row * D_ + col] = b1v * hv + b2v * (accA[i] + bav) + b3v * (accM[i] + bmv);
  }
}

extern "C" void kernel_launch(void* const* d_in, const int* in_sizes, int n_in,
                              void* d_out, int out_size, void* d_ws, size_t ws_size,
                              hipStream_t stream) {
  const float* h   = (const float*)d_in[0];
  const float* Aa  = (const float*)d_in[1];
  const float* Am  = (const float*)d_in[2];
  const float* W1  = (const float*)d_in[3];
  const float* b1  = (const float*)d_in[4];
  const float* W2  = (const float*)d_in[5];
  const float* b2  = (const float*)d_in[6];
  const float* Wa  = (const float*)d_in[7];
  const float* ba  = (const float*)d_in[8];
  const float* Wm  = (const float*)d_in[9];
  const float* bm  = (const float*)d_in[10];
  const float* be1 = (const float*)d_in[11];
  const float* be2 = (const float*)d_in[12];
  const float* be3 = (const float*)d_in[13];
  float* z = (float*)d_out;

  char* wsb = (char*)d_ws;
  __hip_bfloat16* P = (__hip_bfloat16*)wsb;                    // 1MB
  __hip_bfloat16* Q = P + (B_ * C_ * D_);                      // 1MB
  float* SA = (float*)(wsb + 2 * (size_t)(B_ * C_ * D_) * 2);  // [b][v][u], 1MB
  float* AT = SA + (B_ * C_ * C_);                             // 2MB
  float* MT = AT + (B_ * C_ * D_);                             // 2MB

  k1_pq <<<dim3(8, 256),   256, 0, stream>>>(h, W1, b1, P, Q);
  k2_s  <<<dim3(8, 8, 16), 256, 0, stream>>>(P, Q, W2, b2, Aa, SA);
  k3_agg<<<dim3(64, 16),   256, 0, stream>>>(SA, Am, h, AT, MT);
  k4_out<<<dim3(4, 256),   256, 0, stream>>>(h, AT, MT, Wa, ba, Wm, bm, be1, be2, be3, z);
}

// Round 7
// 123.286 us; speedup vs baseline: 1.2554x; 1.1950x over previous
//
#include <hip/hip_runtime.h>
#include <hip/hip_bf16.h>

#define B_ 16
#define C_ 128
#define D_ 256

typedef unsigned int uint32;
typedef unsigned short u16;
typedef __attribute__((ext_vector_type(8))) short s8v;   // 8 bf16 = 4 VGPR
typedef __attribute__((ext_vector_type(4))) float f4v;   // MFMA acc

__device__ __forceinline__ u16 bfu(float x) {
  union { __hip_bfloat16 h; u16 s; } u;
  u.h = __float2bfloat16(x);
  return u.s;
}
__device__ __forceinline__ float2 bf2x(uint32 x) {
  return make_float2(__uint_as_float(x << 16), __uint_as_float(x & 0xffff0000u));
}

// ---------------------------------------------------------------------------
// PREP: bf16 casts + transposes so every MFMA fragment load is 16B contiguous.
//  hb    [2048][256]  = bf16(h)                (k1 A operand)
//  hbT   [16][256][128] = bf16(h^T per batch)  (k3 B operand)
//  w1t   [512 n][256 k]: n<256 -> W1[k][n] ; n>=256 -> W1[256+k][n-256]  (k1 B)
//  wcatT [256 n][512 k]: k<256 -> b2*Wa[k][n] ; else b3*Wm[k-256][n]     (k4 B)
//  amT   [128 v][128 u] = bf16(Am[u][v])       (k3 A2)
//  bcat  [256] = b2*ba + b3*bm (fp32)
// ---------------------------------------------------------------------------
__global__ __launch_bounds__(256) void kprep(const float* __restrict__ h,
    const float* __restrict__ W1, const float* __restrict__ Wa,
    const float* __restrict__ Wm, const float* __restrict__ Am,
    const float* __restrict__ ba, const float* __restrict__ bm,
    const float* __restrict__ be2, const float* __restrict__ be3,
    u16* __restrict__ hb, u16* __restrict__ hbT, u16* __restrict__ w1t,
    u16* __restrict__ wcatT, u16* __restrict__ amT, float* __restrict__ bcat) {
  const int idx0 = blockIdx.x * 256 + threadIdx.x;
  const int stride = gridDim.x * 256;
  const float b2v = be2[0], b3v = be3[0];
  for (int i = idx0; i < B_ * C_ * D_; i += stride) hb[i] = bfu(h[i]);
  for (int i = idx0; i < B_ * C_ * D_; i += stride) {
    const int b = i >> 15, r = i & 32767, d = r >> 7, u = r & 127;
    hbT[i] = bfu(h[(b * C_ + u) * D_ + d]);
  }
  for (int i = idx0; i < 512 * 256; i += stride) {
    const int n = i >> 8, k = i & 255;
    const float v = (n < 256) ? W1[k * 256 + n] : W1[(256 + k) * 256 + (n - 256)];
    w1t[i] = bfu(v);
  }
  for (int i = idx0; i < 256 * 512; i += stride) {
    const int n = i >> 9, k = i & 511;
    const float v = (k < 256) ? b2v * Wa[k * 256 + n] : b3v * Wm[(k - 256) * 256 + n];
    wcatT[i] = bfu(v);
  }
  for (int i = idx0; i < C_ * C_; i += stride) {
    const int v = i >> 7, u = i & 127;
    amT[i] = bfu(Am[u * C_ + v]);
  }
  for (int i = idx0; i < D_; i += stride) bcat[i] = b2v * ba[i] + b3v * bm[i];
}

// ---------------------------------------------------------------------------
// K1 (MFMA): [P|Q](2048 x 512) = hb(2048x256) @ w1t^T ; Q += b1.
// 4096 waves (128 mt x 32 nt), 16x16 tile each, K=256 -> 8 MFMA.
// Fragments straight from global (L2-hot), no LDS.
// ---------------------------------------------------------------------------
__global__ __launch_bounds__(256) void k1_mfma(const u16* __restrict__ hb,
    const u16* __restrict__ w1t, const float* __restrict__ b1,
    u16* __restrict__ P, u16* __restrict__ Q) {
  const int lane = threadIdx.x & 63;
  const int w = blockIdx.x * 4 + (threadIdx.x >> 6);  // 0..4095
  const int nt = w & 31, mt = w >> 5;
  const int row0 = mt * 16, col0 = nt * 16;
  const int lr = lane & 15, lk = lane >> 4;
  const u16* ap = hb + (row0 + lr) * D_ + lk * 8;
  const u16* bp = w1t + (col0 + lr) * D_ + lk * 8;
  f4v acc = {0.f, 0.f, 0.f, 0.f};
#pragma unroll
  for (int ks = 0; ks < 8; ++ks) {
    const s8v af = *(const s8v*)(ap + ks * 32);
    const s8v bf = *(const s8v*)(bp + ks * 32);
    acc = __builtin_amdgcn_mfma_f32_16x16x32_bf16(af, bf, acc, 0, 0, 0);
  }
  const int col = col0 + lr;
  if (col0 < 256) {
#pragma unroll
    for (int r = 0; r < 4; ++r) {
      const int row = row0 + lk * 4 + r;
      P[row * D_ + col] = bfu(acc[r]);
    }
  } else {
    const float bb = b1[col - 256];
#pragma unroll
    for (int r = 0; r < 4; ++r) {
      const int row = row0 + lk * 4 + r;
      Q[row * D_ + (col - 256)] = bfu(acc[r] + bb);
    }
  }
}

// ---------------------------------------------------------------------------
// K2 (VALU, irreducible relu-dot):
// SA_T[b,v,u] = sigmoid( sum_k relu(P[b,u,k]+Q[b,v,k])*W2[k]+b2 ) * Aa[u,v]
// 16x16 uv-tile; P/Q packed bf16 in LDS, pad 130 (row stride 520B: 8B-aligned,
// b64 reads conflict-free); W2 via wave-uniform float4. Grid 1024 blocks.
// ---------------------------------------------------------------------------
__global__ __launch_bounds__(256) void k2_s(const u16* __restrict__ P,
    const u16* __restrict__ Q, const float* __restrict__ W2,
    const float* __restrict__ b2, const float* __restrict__ Aa,
    float* __restrict__ SA) {
  const int b = blockIdx.z;
  const int u0 = blockIdx.x * 16;
  const int v0 = blockIdx.y * 16;
  const int tid = threadIdx.x;
  __shared__ uint32 Pl[16][130];
  __shared__ uint32 Ql[16][130];
  const uint32* Pg = (const uint32*)(P + (b * C_ + u0) * D_);
  const uint32* Qg = (const uint32*)(Q + (b * C_ + v0) * D_);
#pragma unroll
  for (int i = 0; i < 8; ++i) {
    const int idx = i * 256 + tid;
    const int r = idx >> 7, kk = idx & 127;
    Pl[r][kk] = Pg[r * 128 + kk];
    Ql[r][kk] = Qg[r * 128 + kk];
  }
  __syncthreads();
  const int ul = tid & 15;
  const int vl = tid >> 4;
  const float4* __restrict__ w4 = (const float4*)W2;
  float a0 = 0.f, a1 = 0.f;
#pragma unroll 8
  for (int kk = 0; kk < 128; kk += 2) {
    const uint2 pu = *(const uint2*)&Pl[ul][kk];
    const uint2 qu = *(const uint2*)&Ql[vl][kk];
    const float4 wv = w4[kk >> 1];
    const float2 p0 = bf2x(pu.x), p1 = bf2x(pu.y);
    const float2 q0 = bf2x(qu.x), q1 = bf2x(qu.y);
    a0 = fmaf(fmaxf(p0.x + q0.x, 0.f), wv.x, a0);
    a0 = fmaf(fmaxf(p0.y + q0.y, 0.f), wv.y, a0);
    a1 = fmaf(fmaxf(p1.x + q1.x, 0.f), wv.z, a1);
    a1 = fmaf(fmaxf(p1.y + q1.y, 0.f), wv.w, a1);
  }
  const float s = 1.f / (1.f + __expf(-(a0 + a1 + b2[0])));
  const int u = u0 + ul, v = v0 + vl;
  SA[b * C_ * C_ + v * C_ + u] = s * Aa[u * C_ + v];
}

// ---------------------------------------------------------------------------
// K3 (MFMA): per batch b: a_t = SA_T(128x128) @ h(128x256);
// m_t = (AmT(128x128) @ h) .* h.  Both share the B fragment (hbT) ->
// one wave computes BOTH 16x16 tiles (2 acc sets), K=128 -> 4+4 MFMA.
// SA is fp32 (accuracy): convert to bf16 fragment in-register.
// Output: atcat[row][0:256]=a_t bf16, [256:512]=m_t bf16 (k4's A, k-major).
// 2048 waves (16 b x 8 mt x 16 nt) -> 512 blocks.
// ---------------------------------------------------------------------------
__global__ __launch_bounds__(256) void k3_mfma(const float* __restrict__ SA,
    const u16* __restrict__ amT, const u16* __restrict__ hbT,
    const float* __restrict__ h, u16* __restrict__ atcat) {
  const int lane = threadIdx.x & 63;
  const int w = blockIdx.x * 4 + (threadIdx.x >> 6);  // 0..2047
  const int bt = w >> 7, rem = w & 127;
  const int mt = rem >> 4, nt = rem & 15;
  const int v0 = mt * 16, d0 = nt * 16;
  const int lr = lane & 15, lk = lane >> 4;
  const float* sap = SA + (bt * C_ + v0 + lr) * C_ + lk * 8;
  const u16* a2p = amT + (v0 + lr) * C_ + lk * 8;
  const u16* bp = hbT + (bt * D_ + d0 + lr) * C_ + lk * 8;
  f4v acca = {0.f, 0.f, 0.f, 0.f}, accm = {0.f, 0.f, 0.f, 0.f};
#pragma unroll
  for (int ks = 0; ks < 4; ++ks) {
    const float4 f0 = *(const float4*)(sap + ks * 32);
    const float4 f1 = *(const float4*)(sap + ks * 32 + 4);
    union { s8v v; u16 u[8]; } a1;
    a1.u[0] = bfu(f0.x); a1.u[1] = bfu(f0.y); a1.u[2] = bfu(f0.z); a1.u[3] = bfu(f0.w);
    a1.u[4] = bfu(f1.x); a1.u[5] = bfu(f1.y); a1.u[6] = bfu(f1.z); a1.u[7] = bfu(f1.w);
    const s8v a2 = *(const s8v*)(a2p + ks * 32);
    const s8v bf = *(const s8v*)(bp + ks * 32);
    acca = __builtin_amdgcn_mfma_f32_16x16x32_bf16(a1.v, bf, acca, 0, 0, 0);
    accm = __builtin_amdgcn_mfma_f32_16x16x32_bf16(a2, bf, accm, 0, 0, 0);
  }
  const int d = d0 + lr;
#pragma unroll
  for (int r = 0; r < 4; ++r) {
    const int vrow = v0 + lk * 4 + r;
    const int grow = bt * C_ + vrow;
    atcat[grow * 512 + d] = bfu(acca[r]);
    const float hv = h[grow * D_ + d];
    atcat[grow * 512 + 256 + d] = bfu(accm[r] * hv);
  }
}

// ---------------------------------------------------------------------------
// K4 (MFMA): z(2048x256) = atcat(2048x512) @ wcatT^T  (betas pre-folded)
//            + beta1*h + bcat.  K=512 -> 16 MFMA/wave.
// 2048 waves (128 mt x 16 nt) -> 512 blocks.
// ---------------------------------------------------------------------------
__global__ __launch_bounds__(256) void k4_mfma(const u16* __restrict__ atcat,
    const u16* __restrict__ wcatT, const float* __restrict__ bcat,
    const float* __restrict__ h, const float* __restrict__ be1,
    float* __restrict__ z) {
  const int lane = threadIdx.x & 63;
  const int w = blockIdx.x * 4 + (threadIdx.x >> 6);  // 0..2047
  const int nt = w & 15, mt = w >> 4;
  const int row0 = mt * 16, col0 = nt * 16;
  const int lr = lane & 15, lk = lane >> 4;
  const u16* ap = atcat + (row0 + lr) * 512 + lk * 8;
  const u16* bp = wcatT + (col0 + lr) * 512 + lk * 8;
  f4v acc = {0.f, 0.f, 0.f, 0.f};
#pragma unroll
  for (int ks = 0; ks < 16; ++ks) {
    const s8v af = *(const s8v*)(ap + ks * 32);
    const s8v bf = *(const s8v*)(bp + ks * 32);
    acc = __builtin_amdgcn_mfma_f32_16x16x32_bf16(af, bf, acc, 0, 0, 0);
  }
  const float b1v = be1[0];
  const int col = col0 + lr;
  const float bc = bcat[col];
#pragma unroll
  for (int r = 0; r < 4; ++r) {
    const int row = row0 + lk * 4 + r;
    z[row * D_ + col] = acc[r] + b1v * h[row * D_ + col] + bc;
  }
}

extern "C" void kernel_launch(void* const* d_in, const int* in_sizes, int n_in,
                              void* d_out, int out_size, void* d_ws, size_t ws_size,
                              hipStream_t stream) {
  const float* h   = (const float*)d_in[0];
  const float* Aa  = (const float*)d_in[1];
  const float* Am  = (const float*)d_in[2];
  const float* W1  = (const float*)d_in[3];
  const float* b1  = (const float*)d_in[4];
  const float* W2  = (const float*)d_in[5];
  const float* b2  = (const float*)d_in[6];
  const float* Wa  = (const float*)d_in[7];
  const float* ba  = (const float*)d_in[8];
  const float* Wm  = (const float*)d_in[9];
  const float* bm  = (const float*)d_in[10];
  const float* be1 = (const float*)d_in[11];
  const float* be2 = (const float*)d_in[12];
  const float* be3 = (const float*)d_in[13];
  float* z = (float*)d_out;

  char* wsb = (char*)d_ws;
  u16*   hb    = (u16*)(wsb);                               // 1 MB
  u16*   hbT   = (u16*)(wsb + (1 << 20));                   // 1 MB
  u16*   w1t   = (u16*)(wsb + (2 << 20));                   // 256 KB
  u16*   wcatT = (u16*)(wsb + (2 << 20) + (256 << 10));     // 256 KB
  u16*   amT   = (u16*)(wsb + (2 << 20) + (512 << 10));     // 32 KB
  float* bcat  = (float*)(wsb + (2 << 20) + (544 << 10));   // 1 KB
  u16*   P     = (u16*)(wsb + (3 << 20));                   // 1 MB
  u16*   Q     = (u16*)(wsb + (4 << 20));                   // 1 MB
  float* SA    = (float*)(wsb + (5 << 20));                 // 1 MB  [b][v][u]
  u16*   atcat = (u16*)(wsb + (6 << 20));                   // 2 MB  [row][512]

  kprep  <<<1024, 256, 0, stream>>>(h, W1, Wa, Wm, Am, ba, bm, be2, be3,
                                    hb, hbT, w1t, wcatT, amT, bcat);
  k1_mfma<<<1024, 256, 0, stream>>>(hb, w1t, b1, P, Q);
  k2_s   <<<dim3(8, 8, 16), 256, 0, stream>>>(P, Q, W2, b2, Aa, SA);
  k3_mfma<<<512, 256, 0, stream>>>(SA, amT, hbT, h, atcat);
  k4_mfma<<<512, 256, 0, stream>>>(atcat, wcatT, bcat, h, be1, z);
}

// Round 9
// 121.246 us; speedup vs baseline: 1.2765x; 1.0168x over previous
//
#include <hip/hip_runtime.h>
#include <hip/hip_bf16.h>

#define B_ 16
#define C_ 128
#define D_ 256

typedef unsigned int uint32;
typedef unsigned short u16;
typedef __attribute__((ext_vector_type(8))) short s8v;   // 8 bf16 = 4 VGPR
typedef __attribute__((ext_vector_type(4))) float f4v;   // MFMA acc

__device__ __forceinline__ u16 bfu(float x) {
  union { __hip_bfloat16 h; u16 s; } u;
  u.h = __float2bfloat16(x);
  return u.s;
}
__device__ __forceinline__ float2 bf2x(uint32 x) {
  return make_float2(__uint_as_float(x << 16), __uint_as_float(x & 0xffff0000u));
}

// ---------------------------------------------------------------------------
// PREP (task-partitioned for max MLP; every thread: <=4 independent loads,
// one 8B store):
//  blocks [0,512):    hb   [2048][256] = bf16(h)
//  blocks [512,1024): hbT  [16][256][128] = bf16(h^T per batch)
//  blocks [1024,1152):w1t  [512 n][256 k]: n<256 -> W1[k][n]; else W1[256+k][n-256]
//  blocks [1152,1280):wcatT[256 n][512 k]: k<256 -> b2*Wa[k][n]; else b3*Wm[k-256][n]
//  blocks [1280,1296):amT  [128 v][128 u] = bf16(Am[u][v])
//  block  1296:       bcat [256] = b2*ba + b3*bm (fp32)
// ---------------------------------------------------------------------------
__global__ __launch_bounds__(256) void kprep(const float* __restrict__ h,
    const float* __restrict__ W1, const float* __restrict__ Wa,
    const float* __restrict__ Wm, const float* __restrict__ Am,
    const float* __restrict__ ba, const float* __restrict__ bm,
    const float* __restrict__ be2, const float* __restrict__ be3,
    u16* __restrict__ hb, u16* __restrict__ hbT, u16* __restrict__ w1t,
    u16* __restrict__ wcatT, u16* __restrict__ amT, float* __restrict__ bcat) {
  const int blk = blockIdx.x;
  const int tid = threadIdx.x;
  if (blk < 512) {
    const int i4 = (blk * 256 + tid) * 4;
    const float4 v = *(const float4*)(h + i4);
    ushort4 o; o.x = bfu(v.x); o.y = bfu(v.y); o.z = bfu(v.z); o.w = bfu(v.w);
    *(ushort4*)(hb + i4) = o;
  } else if (blk < 1024) {
    const int i4 = ((blk - 512) * 256 + tid) * 4;     // hbT flat index
    const int b = i4 >> 15;
    const int r = i4 & 32767;
    const int d = r >> 7, u0 = r & 127;
    const float x0 = h[(b * C_ + u0 + 0) * D_ + d];
    const float x1 = h[(b * C_ + u0 + 1) * D_ + d];
    const float x2 = h[(b * C_ + u0 + 2) * D_ + d];
    const float x3 = h[(b * C_ + u0 + 3) * D_ + d];
    ushort4 o; o.x = bfu(x0); o.y = bfu(x1); o.z = bfu(x2); o.w = bfu(x3);
    *(ushort4*)(hbT + i4) = o;
  } else if (blk < 1152) {
    const int i4 = ((blk - 1024) * 256 + tid) * 4;    // w1t flat [n][k]
    const int n = i4 >> 8, k0 = i4 & 255;
    float x0, x1, x2, x3;
    if (n < 256) {
      x0 = W1[(k0 + 0) * 256 + n]; x1 = W1[(k0 + 1) * 256 + n];
      x2 = W1[(k0 + 2) * 256 + n]; x3 = W1[(k0 + 3) * 256 + n];
    } else {
      const int nn = n - 256;
      x0 = W1[(256 + k0 + 0) * 256 + nn]; x1 = W1[(256 + k0 + 1) * 256 + nn];
      x2 = W1[(256 + k0 + 2) * 256 + nn]; x3 = W1[(256 + k0 + 3) * 256 + nn];
    }
    ushort4 o; o.x = bfu(x0); o.y = bfu(x1); o.z = bfu(x2); o.w = bfu(x3);
    *(ushort4*)(w1t + i4) = o;
  } else if (blk < 1280) {
    const float b2v = be2[0], b3v = be3[0];
    const int i4 = ((blk - 1152) * 256 + tid) * 4;    // wcatT flat [n][k]
    const int n = i4 >> 9, k0 = i4 & 511;
    float x0, x1, x2, x3;
    if (k0 < 256) {
      x0 = b2v * Wa[(k0 + 0) * 256 + n]; x1 = b2v * Wa[(k0 + 1) * 256 + n];
      x2 = b2v * Wa[(k0 + 2) * 256 + n]; x3 = b2v * Wa[(k0 + 3) * 256 + n];
    } else {
      const int kk = k0 - 256;
      x0 = b3v * Wm[(kk + 0) * 256 + n]; x1 = b3v * Wm[(kk + 1) * 256 + n];
      x2 = b3v * Wm[(kk + 2) * 256 + n]; x3 = b3v * Wm[(kk + 3) * 256 + n];
    }
    ushort4 o; o.x = bfu(x0); o.y = bfu(x1); o.z = bfu(x2); o.w = bfu(x3);
    *(ushort4*)(wcatT + i4) = o;
  } else if (blk < 1296) {
    const int i4 = ((blk - 1280) * 256 + tid) * 4;    // amT flat [v][u]
    const int v = i4 >> 7, u0 = i4 & 127;
    const float x0 = Am[(u0 + 0) * C_ + v];
    const float x1 = Am[(u0 + 1) * C_ + v];
    const float x2 = Am[(u0 + 2) * C_ + v];
    const float x3 = Am[(u0 + 3) * C_ + v];
    ushort4 o; o.x = bfu(x0); o.y = bfu(x1); o.z = bfu(x2); o.w = bfu(x3);
    *(ushort4*)(amT + i4) = o;
  } else {
    const float b2v = be2[0], b3v = be3[0];
    bcat[tid] = b2v * ba[tid] + b3v * bm[tid];
  }
}

// ---------------------------------------------------------------------------
// K1 (MFMA): [P|Q](2048 x 512) = hb(2048x256) @ w1t^T ; Q += b1.
// 4096 waves (128 mt x 32 nt), 16x16 tile, K=256 -> 8 MFMA, 16 dwordx4 loads
// all independent (full MLP). Grid 1024 blocks.
// ---------------------------------------------------------------------------
__global__ __launch_bounds__(256) void k1_mfma(const u16* __restrict__ hb,
    const u16* __restrict__ w1t, const float* __restrict__ b1,
    u16* __restrict__ P, u16* __restrict__ Q) {
  const int lane = threadIdx.x & 63;
  const int w = blockIdx.x * 4 + (threadIdx.x >> 6);
  const int nt = w & 31, mt = w >> 5;
  const int row0 = mt * 16, col0 = nt * 16;
  const int lr = lane & 15, lk = lane >> 4;
  const u16* ap = hb + (row0 + lr) * D_ + lk * 8;
  const u16* bp = w1t + (col0 + lr) * D_ + lk * 8;
  f4v acc = {0.f, 0.f, 0.f, 0.f};
#pragma unroll
  for (int ks = 0; ks < 8; ++ks) {
    const s8v af = *(const s8v*)(ap + ks * 32);
    const s8v bf = *(const s8v*)(bp + ks * 32);
    acc = __builtin_amdgcn_mfma_f32_16x16x32_bf16(af, bf, acc, 0, 0, 0);
  }
  const int col = col0 + lr;
  if (col0 < 256) {
#pragma unroll
    for (int r = 0; r < 4; ++r)
      P[(row0 + lk * 4 + r) * D_ + col] = bfu(acc[r]);
  } else {
    const float bb = b1[col - 256];
#pragma unroll
    for (int r = 0; r < 4; ++r)
      Q[(row0 + lk * 4 + r) * D_ + (col - 256)] = bfu(acc[r] + bb);
  }
}

// ---------------------------------------------------------------------------
// K2 (VALU, irreducible relu-dot):
// SA_T[b,v,u] = bf16( sigmoid( sum_k relu(P[b,u,k]+Q[b,v,k])*W2[k]+b2 ) * Aa[u,v] )
// 16x16 uv-tile; P/Q packed bf16 in LDS (pad 130 -> 8B-aligned rows).
// Staging: uint4 global load per row-half (full 128 cols), two uint2 LDS
// stores. Grid (8,8,16)=1024 blocks.
// ---------------------------------------------------------------------------
__global__ __launch_bounds__(256) void k2_s(const u16* __restrict__ P,
    const u16* __restrict__ Q, const float* __restrict__ W2,
    const float* __restrict__ b2, const float* __restrict__ Aa,
    u16* __restrict__ SA) {
  const int b = blockIdx.z;
  const int u0 = blockIdx.x * 16;
  const int v0 = blockIdx.y * 16;
  const int tid = threadIdx.x;
  __shared__ uint32 Pl[16][130];
  __shared__ uint32 Ql[16][130];
  const uint32* Pg = (const uint32*)(P + (b * C_ + u0) * D_);
  const uint32* Qg = (const uint32*)(Q + (b * C_ + v0) * D_);
  {  // 16 rows x 128 uint32 each: per thread 2 halves x uint4 (4 cols)
    const int r = tid >> 5;            // 0..7
    const int c4 = (tid & 31) * 4;     // 0,4,...,124
#pragma unroll
    for (int half = 0; half < 2; ++half) {
      const int rr = r + half * 8;
      const uint4 pv = *(const uint4*)&Pg[rr * 128 + c4];
      const uint4 qv = *(const uint4*)&Qg[rr * 128 + c4];
      *(uint2*)&Pl[rr][c4]     = make_uint2(pv.x, pv.y);
      *(uint2*)&Pl[rr][c4 + 2] = make_uint2(pv.z, pv.w);
      *(uint2*)&Ql[rr][c4]     = make_uint2(qv.x, qv.y);
      *(uint2*)&Ql[rr][c4 + 2] = make_uint2(qv.z, qv.w);
    }
  }
  __syncthreads();
  const int ul = tid & 15;
  const int vl = tid >> 4;
  const float4* __restrict__ w4 = (const float4*)W2;
  float a0 = 0.f, a1 = 0.f;
#pragma unroll 8
  for (int kk = 0; kk < 128; kk += 2) {
    const uint2 pu = *(const uint2*)&Pl[ul][kk];
    const uint2 qu = *(const uint2*)&Ql[vl][kk];
    const float4 wv = w4[kk >> 1];
    const float2 p0 = bf2x(pu.x), p1 = bf2x(pu.y);
    const float2 q0 = bf2x(qu.x), q1 = bf2x(qu.y);
    a0 = fmaf(fmaxf(p0.x + q0.x, 0.f), wv.x, a0);
    a0 = fmaf(fmaxf(p0.y + q0.y, 0.f), wv.y, a0);
    a1 = fmaf(fmaxf(p1.x + q1.x, 0.f), wv.z, a1);
    a1 = fmaf(fmaxf(p1.y + q1.y, 0.f), wv.w, a1);
  }
  const float s = 1.f / (1.f + __expf(-(a0 + a1 + b2[0])));
  const int u = u0 + ul, v = v0 + vl;
  SA[b * C_ * C_ + v * C_ + u] = bfu(s * Aa[u * C_ + v]);
}

// ---------------------------------------------------------------------------
// K3 (MFMA): per batch: a_t = SA_T @ h ; m_t = (AmT @ h) .* h. Shared B frag.
// SA bf16 -> direct s8v loads. K=128 -> 4+4 MFMA.
// Output atcat[row][0:256]=a_t, [256:512]=m_t (bf16). 512 blocks.
// ---------------------------------------------------------------------------
__global__ __launch_bounds__(256) void k3_mfma(const u16* __restrict__ SA,
    const u16* __restrict__ amT, const u16* __restrict__ hbT,
    const float* __restrict__ h, u16* __restrict__ atcat) {
  const int lane = threadIdx.x & 63;
  const int w = blockIdx.x * 4 + (threadIdx.x >> 6);  // 0..2047
  const int bt = w >> 7, rem = w & 127;
  const int mt = rem >> 4, nt = rem & 15;
  const int v0 = mt * 16, d0 = nt * 16;
  const int lr = lane & 15, lk = lane >> 4;
  const u16* sap = SA + (bt * C_ + v0 + lr) * C_ + lk * 8;
  const u16* a2p = amT + (v0 + lr) * C_ + lk * 8;
  const u16* bp = hbT + (bt * D_ + d0 + lr) * C_ + lk * 8;
  f4v acca = {0.f, 0.f, 0.f, 0.f}, accm = {0.f, 0.f, 0.f, 0.f};
#pragma unroll
  for (int ks = 0; ks < 4; ++ks) {
    const s8v a1 = *(const s8v*)(sap + ks * 32);
    const s8v a2 = *(const s8v*)(a2p + ks * 32);
    const s8v bf = *(const s8v*)(bp + ks * 32);
    acca = __builtin_amdgcn_mfma_f32_16x16x32_bf16(a1, bf, acca, 0, 0, 0);
    accm = __builtin_amdgcn_mfma_f32_16x16x32_bf16(a2, bf, accm, 0, 0, 0);
  }
  const int d = d0 + lr;
#pragma unroll
  for (int r = 0; r < 4; ++r) {
    const int grow = bt * C_ + v0 + lk * 4 + r;
    atcat[grow * 512 + d] = bfu(acca[r]);
    const float hv = h[grow * D_ + d];
    atcat[grow * 512 + 256 + d] = bfu(accm[r] * hv);
  }
}

// ---------------------------------------------------------------------------
// K4 (MFMA): z = atcat(2048x512) @ wcatT^T + beta1*h + bcat. K=512 -> 16 MFMA.
// 2048 waves -> 512 blocks.
// ---------------------------------------------------------------------------
__global__ __launch_bounds__(256) void k4_mfma(const u16* __restrict__ atcat,
    const u16* __restrict__ wcatT, const float* __restrict__ bcat,
    const float* __restrict__ h, const float* __restrict__ be1,
    float* __restrict__ z) {
  const int lane = threadIdx.x & 63;
  const int w = blockIdx.x * 4 + (threadIdx.x >> 6);
  const int nt = w & 15, mt = w >> 4;
  const int row0 = mt * 16, col0 = nt * 16;
  const int lr = lane & 15, lk = lane >> 4;
  const u16* ap = atcat + (row0 + lr) * 512 + lk * 8;
  const u16* bp = wcatT + (col0 + lr) * 512 + lk * 8;
  f4v acc = {0.f, 0.f, 0.f, 0.f};
#pragma unroll
  for (int ks = 0; ks < 16; ++ks) {
    const s8v af = *(const s8v*)(ap + ks * 32);
    const s8v bf = *(const s8v*)(bp + ks * 32);
    acc = __builtin_amdgcn_mfma_f32_16x16x32_bf16(af, bf, acc, 0, 0, 0);
  }
  const float b1v = be1[0];
  const int col = col0 + lr;
  const float bc = bcat[col];
#pragma unroll
  for (int r = 0; r < 4; ++r) {
    const int row = row0 + lk * 4 + r;
    z[row * D_ + col] = acc[r] + b1v * h[row * D_ + col] + bc;
  }
}

extern "C" void kernel_launch(void* const* d_in, const int* in_sizes, int n_in,
                              void* d_out, int out_size, void* d_ws, size_t ws_size,
                              hipStream_t stream) {
  const float* h   = (const float*)d_in[0];
  const float* Aa  = (const float*)d_in[1];
  const float* Am  = (const float*)d_in[2];
  const float* W1  = (const float*)d_in[3];
  const float* b1  = (const float*)d_in[4];
  const float* W2  = (const float*)d_in[5];
  const float* b2  = (const float*)d_in[6];
  const float* Wa  = (const float*)d_in[7];
  const float* ba  = (const float*)d_in[8];
  const float* Wm  = (const float*)d_in[9];
  const float* bm  = (const float*)d_in[10];
  const float* be1 = (const float*)d_in[11];
  const float* be2 = (const float*)d_in[12];
  const float* be3 = (const float*)d_in[13];
  float* z = (float*)d_out;

  char* wsb = (char*)d_ws;
  u16*   hb    = (u16*)(wsb);                               // 1 MB
  u16*   hbT   = (u16*)(wsb + (1 << 20));                   // 1 MB
  u16*   w1t   = (u16*)(wsb + (2 << 20));                   // 256 KB
  u16*   wcatT = (u16*)(wsb + (2 << 20) + (256 << 10));     // 256 KB
  u16*   amT   = (u16*)(wsb + (2 << 20) + (512 << 10));     // 32 KB
  float* bcat  = (float*)(wsb + (2 << 20) + (544 << 10));   // 1 KB
  u16*   P     = (u16*)(wsb + (3 << 20));                   // 1 MB
  u16*   Q     = (u16*)(wsb + (4 << 20));                   // 1 MB
  u16*   SA    = (u16*)(wsb + (5 << 20));                   // 512 KB [b][v][u]
  u16*   atcat = (u16*)(wsb + (6 << 20));                   // 2 MB  [row][512]

  kprep  <<<1297, 256, 0, stream>>>(h, W1, Wa, Wm, Am, ba, bm, be2, be3,
                                    hb, hbT, w1t, wcatT, amT, bcat);
  k1_mfma<<<1024, 256, 0, stream>>>(hb, w1t, b1, P, Q);
  k2_s   <<<dim3(8, 8, 16), 256, 0, stream>>>(P, Q, W2, b2, Aa, SA);
  k3_mfma<<<512, 256, 0, stream>>>(SA, amT, hbT, h, atcat);
  k4_mfma<<<512, 256, 0, stream>>>(atcat, wcatT, bcat, h, be1, z);
}